// Round 1
// baseline (1067.288 us; speedup 1.0000x reference)
//
#include <hip/hip_runtime.h>

// Problem: B=16, T=2048, D=512, H=512, K=2
// M = B*T = 32768 rows, GEMM K-dim = D*K = 1024, N = 3H = 1536.
//
// ws layout (bytes):
//   Abf   [32768][1024] bf16 @ 0          (67,108,864)
//   Bbf   [1536][1024]  bf16 @ 67108864   ( 3,145,728)
//   gates [32768][1536] bf16 @ 70254592   (100,663,296)   pre-activation!
// total 170,917,888 B

#define MTOT 32768
#define NTOT 1536
#define KTOT 1024
#define DCH  512
#define TLEN 2048
#define NB   16

typedef __bf16 bf16x8 __attribute__((ext_vector_type(8)));
typedef float  f32x4  __attribute__((ext_vector_type(4)));

__device__ __forceinline__ unsigned short f2bf(float x) {
    unsigned u = __float_as_uint(x);
    u += 0x7FFFu + ((u >> 16) & 1u);   // round-to-nearest-even
    return (unsigned short)(u >> 16);
}
__device__ __forceinline__ float bf2f(unsigned short h) {
    return __uint_as_float(((unsigned)h) << 16);
}

// ---------------------------------------------------------------------------
// K0: build A bf16 [M][1024]: A[m][j] = in[(m-1)*512 + j], zero when t==0 && j<512
// one thread per 8 elements
__global__ __launch_bounds__(256) void make_A(const float* __restrict__ in,
                                              unsigned short* __restrict__ A) {
    size_t i = (size_t)blockIdx.x * 256 + threadIdx.x;
    size_t e = i * 8;                       // element offset in A
    size_t m = e >> 10;
    int    j = (int)(e & 1023);
    alignas(16) unsigned short h[8];
    if (((m & (TLEN - 1)) == 0) && (j < DCH)) {
#pragma unroll
        for (int r = 0; r < 8; ++r) h[r] = 0;
    } else {
        const float* src = in + ((long long)m - 1) * DCH + j;
        float4 a = *(const float4*)src;
        float4 b = *(const float4*)(src + 4);
        h[0] = f2bf(a.x); h[1] = f2bf(a.y); h[2] = f2bf(a.z); h[3] = f2bf(a.w);
        h[4] = f2bf(b.x); h[5] = f2bf(b.y); h[6] = f2bf(b.z); h[7] = f2bf(b.w);
    }
    *(int4*)(A + e) = *(const int4*)h;
}

// ---------------------------------------------------------------------------
// K1: build B bf16 [N][1024]: Bt[o][kc*512 + d] = w[o*1024 + d*2 + kc]
// one thread per (o, d)
__global__ __launch_bounds__(256) void make_B(const float* __restrict__ w,
                                              unsigned short* __restrict__ Bt) {
    int i = blockIdx.x * 256 + threadIdx.x;     // 1536*512 = 786432
    int o = i >> 9, d = i & 511;
    float w0 = w[(size_t)(o * 512 + d) * 2];
    float w1 = w[(size_t)(o * 512 + d) * 2 + 1];
    Bt[(size_t)o * 1024 + d]       = f2bf(w0);
    Bt[(size_t)o * 1024 + 512 + d] = f2bf(w1);
}

// ---------------------------------------------------------------------------
// K2: GEMM gates[m][n] = sum_k A[m][k] * Bt[n][k]  + bias[n], stored bf16 pre-act.
// 128x128 block tile, BK=32, 4 waves of 4x4 16x16x32 bf16 MFMA.
// LDS tiles stored as [row][4 slots of 16B] with q-slot XOR swizzle
// (physical_q = q ^ ((row>>1)&3)) applied on the GLOBAL fetch side so that
// global_load_lds (lane-linear LDS) + conflict-free ds_read_b128 both work.
__global__ __launch_bounds__(256) void gemm_gates(const unsigned short* __restrict__ A,
                                                  const unsigned short* __restrict__ B,
                                                  const float* __restrict__ bias,
                                                  unsigned short* __restrict__ G) {
    __shared__ int4 sA[512];   // 128 rows x 64B
    __shared__ int4 sB[512];

    const int tid = threadIdx.x;
    const int bx  = blockIdx.x;
    const int mT  = bx / 12, nT = bx % 12;
    const int m0  = mT * 128, n0 = nT * 128;

    // staging: call c covers rows c*64 + (tid>>2); slot qphys = tid&3
    const int mloc = tid >> 2;
    const int qsw  = (tid & 3) ^ ((mloc >> 1) & 3);   // same for both calls (64 rows apart)
    const unsigned short* ga0 = A + (size_t)(m0 + mloc) * 1024 + qsw * 8;
    const unsigned short* ga1 = A + (size_t)(m0 + 64 + mloc) * 1024 + qsw * 8;
    const unsigned short* gb0 = B + (size_t)(n0 + mloc) * 1024 + qsw * 8;
    const unsigned short* gb1 = B + (size_t)(n0 + 64 + mloc) * 1024 + qsw * 8;

    char* la0 = (char*)sA + tid * 16;
    char* la1 = (char*)sA + 4096 + tid * 16;
    char* lb0 = (char*)sB + tid * 16;
    char* lb1 = (char*)sB + 4096 + tid * 16;

    const int lane = tid & 63;
    const int wv   = tid >> 6;
    const int wm   = (wv & 1) * 64, wn = (wv >> 1) * 64;
    const int lr   = lane & 15, lq = lane >> 4;

    int sAidx[4], sBidx[4];
#pragma unroll
    for (int i = 0; i < 4; ++i) {
        int mi = wm + 16 * i + lr;
        sAidx[i] = mi * 4 + (lq ^ ((mi >> 1) & 3));
        int ni = wn + 16 * i + lr;
        sBidx[i] = ni * 4 + (lq ^ ((ni >> 1) & 3));
    }

    f32x4 acc[4][4] = {};

    for (int kt = 0; kt < KTOT; kt += 32) {
        __builtin_amdgcn_global_load_lds(
            (__attribute__((address_space(1))) void*)(void*)ga0,
            (__attribute__((address_space(3))) void*)la0, 16, 0, 0);
        __builtin_amdgcn_global_load_lds(
            (__attribute__((address_space(1))) void*)(void*)ga1,
            (__attribute__((address_space(3))) void*)la1, 16, 0, 0);
        __builtin_amdgcn_global_load_lds(
            (__attribute__((address_space(1))) void*)(void*)gb0,
            (__attribute__((address_space(3))) void*)lb0, 16, 0, 0);
        __builtin_amdgcn_global_load_lds(
            (__attribute__((address_space(1))) void*)(void*)gb1,
            (__attribute__((address_space(3))) void*)lb1, 16, 0, 0);
        ga0 += 32; ga1 += 32; gb0 += 32; gb1 += 32;
        __syncthreads();   // compiler emits vmcnt(0) drain before s_barrier

        bf16x8 af[4], bfr[4];
#pragma unroll
        for (int i = 0; i < 4; ++i) af[i]  = __builtin_bit_cast(bf16x8, sA[sAidx[i]]);
#pragma unroll
        for (int j = 0; j < 4; ++j) bfr[j] = __builtin_bit_cast(bf16x8, sB[sBidx[j]]);

#pragma unroll
        for (int i = 0; i < 4; ++i)
#pragma unroll
            for (int j = 0; j < 4; ++j)
                acc[i][j] = __builtin_amdgcn_mfma_f32_16x16x32_bf16(af[i], bfr[j],
                                                                    acc[i][j], 0, 0, 0);
        __syncthreads();
    }

    // epilogue: C/D layout col = lane&15, row = (lane>>4)*4 + r (measured m89/m91)
#pragma unroll
    for (int j = 0; j < 4; ++j) {
        int gn = n0 + wn + 16 * j + lr;
        float bj = bias[gn];
#pragma unroll
        for (int i = 0; i < 4; ++i) {
            int rowb = m0 + wm + 16 * i + lq * 4;
#pragma unroll
            for (int r = 0; r < 4; ++r) {
                float v = acc[i][j][r] + bj;
                G[(size_t)(rowb + r) * NTOT + gn] = f2bf(v);
            }
        }
    }
}

// ---------------------------------------------------------------------------
// K3: fo-pool scan. 8192 threads = (b,h) chains; activations computed here in fp32.
__global__ __launch_bounds__(256) void scan_fo(const unsigned short* __restrict__ G,
                                               float* __restrict__ out) {
    int idx = blockIdx.x * 256 + threadIdx.x;   // [0, 8192)
    int b = idx >> 9, h = idx & 511;
    const size_t BTH = (size_t)NB * TLEN * DCH;
    const unsigned short* g = G + (size_t)b * TLEN * NTOT + h;
    float* oC  = out + (size_t)b * TLEN * DCH + h;
    float* oOC = out + BTH + (size_t)b * TLEN * DCH + h;

    float c = 0.f;
    unsigned short zg = g[0], fg = g[512], og = g[1024];
    for (int t = 0; t < TLEN; ++t) {
        unsigned short zn = 0, fn = 0, on = 0;
        if (t < TLEN - 1) {
            const unsigned short* gnx = g + NTOT;
            zn = gnx[0]; fn = gnx[512]; on = gnx[1024];
        }
        float zv = bf2f(zg), fv = bf2f(fg), ov = bf2f(og);
        float f = 1.f / (1.f + __expf(-fv));
        float z = 2.f / (1.f + __expf(-2.f * zv)) - 1.f;   // tanh
        float o = 1.f / (1.f + __expf(-ov));
        c = f * c + (1.f - f) * z;
        oC[0]  = c;      oC  += DCH;
        oOC[0] = o * c;  oOC += DCH;
        zg = zn; fg = fn; og = on;
        g += NTOT;
    }
}

// ---------------------------------------------------------------------------
extern "C" void kernel_launch(void* const* d_in, const int* in_sizes, int n_in,
                              void* d_out, int out_size, void* d_ws, size_t ws_size,
                              hipStream_t stream) {
    const float* in   = (const float*)d_in[0];   // [16,2048,512] f32
    const float* w    = (const float*)d_in[1];   // [1536,512,2] f32
    const float* bias = (const float*)d_in[2];   // [1536] f32
    float* out = (float*)d_out;                  // [2][16,2048,512] f32

    unsigned short* Abf   = (unsigned short*)d_ws;
    unsigned short* Bbf   = Abf + (size_t)MTOT * 1024;
    unsigned short* gates = Bbf + (size_t)NTOT * 1024;

    make_A<<<dim3(16384), dim3(256), 0, stream>>>(in, Abf);
    make_B<<<dim3(3072),  dim3(256), 0, stream>>>(w, Bbf);
    gemm_gates<<<dim3(3072), dim3(256), 0, stream>>>(Abf, Bbf, bias, gates);
    scan_fo<<<dim3(32), dim3(256), 0, stream>>>(gates, out);
}

// Round 2
// 407.346 us; speedup vs baseline: 2.6201x; 2.6201x over previous
//
#include <hip/hip_runtime.h>

// Problem: B=16, T=2048, D=512, H=512, K=2
// M = B*T = 32768 rows, GEMM K-dim = D*K = 1024, N = 3H = 1536.
//
// ws layout (bytes):
//   Abf [32768][1024] bf16 @ 0          (67,108,864)
//   Bbf [1536][1024]  bf16 @ 67108864   ( 3,145,728)
//   GT  [1536][32768] bf16 @ 70254592   (100,663,296)  pre-activation, TRANSPOSED
// total 170,917,888 B

#define MTOT 32768
#define NTOT 1536
#define KTOT 1024
#define DCH  512
#define TLEN 2048
#define NB   16

// scan decomposition: each (b,h) chain split into SC chunks of LC steps
#define HT 32     // h per scan block
#define SC 8      // chunks per chain (block covers all of them)
#define LC 256    // t per chunk; SC*LC == TLEN

typedef __bf16 bf16x8 __attribute__((ext_vector_type(8)));
typedef float  f32x4  __attribute__((ext_vector_type(4)));

__device__ __forceinline__ unsigned short f2bf(float x) {
    unsigned u = __float_as_uint(x);
    u += 0x7FFFu + ((u >> 16) & 1u);   // round-to-nearest-even
    return (unsigned short)(u >> 16);
}
__device__ __forceinline__ float bf2f(unsigned short h) {
    return __uint_as_float(((unsigned)h) << 16);
}
__device__ __forceinline__ float sigmoidf_(float x) {
    return 1.f / (1.f + __expf(-x));
}

// ---------------------------------------------------------------------------
// K0: build A bf16 [M][1024]: A[m][j] = in[(m-1)*512 + j], zero when t==0 && j<512
__global__ __launch_bounds__(256) void make_A(const float* __restrict__ in,
                                              unsigned short* __restrict__ A) {
    size_t i = (size_t)blockIdx.x * 256 + threadIdx.x;
    size_t e = i * 8;
    size_t m = e >> 10;
    int    j = (int)(e & 1023);
    alignas(16) unsigned short h[8];
    if (((m & (TLEN - 1)) == 0) && (j < DCH)) {
#pragma unroll
        for (int r = 0; r < 8; ++r) h[r] = 0;
    } else {
        const float* src = in + ((long long)m - 1) * DCH + j;
        float4 a = *(const float4*)src;
        float4 b = *(const float4*)(src + 4);
        h[0] = f2bf(a.x); h[1] = f2bf(a.y); h[2] = f2bf(a.z); h[3] = f2bf(a.w);
        h[4] = f2bf(b.x); h[5] = f2bf(b.y); h[6] = f2bf(b.z); h[7] = f2bf(b.w);
    }
    *(int4*)(A + e) = *(const int4*)h;
}

// ---------------------------------------------------------------------------
// K1: build B bf16 [N][1024]: Bt[o][kc*512 + d] = w[o*1024 + d*2 + kc]
__global__ __launch_bounds__(256) void make_B(const float* __restrict__ w,
                                              unsigned short* __restrict__ Bt) {
    int i = blockIdx.x * 256 + threadIdx.x;     // 1536*512 = 786432
    int o = i >> 9, d = i & 511;
    float w0 = w[(size_t)(o * 512 + d) * 2];
    float w1 = w[(size_t)(o * 512 + d) * 2 + 1];
    Bt[(size_t)o * 1024 + d]       = f2bf(w0);
    Bt[(size_t)o * 1024 + 512 + d] = f2bf(w1);
}

// ---------------------------------------------------------------------------
// K2: GEMM, output TRANSPOSED: GT[n][m] = sum_k A[m][k]*Bt[n][k] + bias[n] (bf16)
// 128x128 tile, BK=32, 4 waves x (4x4) 16x16x32 bf16 MFMA, global_load_lds
// staging with XOR swizzle folded into the global address (LDS stays lane-linear).
__global__ __launch_bounds__(256) void gemm_gates(const unsigned short* __restrict__ A,
                                                  const unsigned short* __restrict__ B,
                                                  const float* __restrict__ bias,
                                                  unsigned short* __restrict__ GT) {
    __shared__ int4 sA[512];   // 128 rows x 64B
    __shared__ int4 sB[512];

    const int tid = threadIdx.x;
    const int bx  = blockIdx.x;
    const int mT  = bx / 12, nT = bx % 12;
    const int m0  = mT * 128, n0 = nT * 128;

    const int mloc = tid >> 2;
    const int qsw  = (tid & 3) ^ ((mloc >> 1) & 3);
    const unsigned short* ga0 = A + (size_t)(m0 + mloc) * 1024 + qsw * 8;
    const unsigned short* ga1 = A + (size_t)(m0 + 64 + mloc) * 1024 + qsw * 8;
    const unsigned short* gb0 = B + (size_t)(n0 + mloc) * 1024 + qsw * 8;
    const unsigned short* gb1 = B + (size_t)(n0 + 64 + mloc) * 1024 + qsw * 8;

    char* la0 = (char*)sA + tid * 16;
    char* la1 = (char*)sA + 4096 + tid * 16;
    char* lb0 = (char*)sB + tid * 16;
    char* lb1 = (char*)sB + 4096 + tid * 16;

    const int lane = tid & 63;
    const int wv   = tid >> 6;
    const int wm   = (wv & 1) * 64, wn = (wv >> 1) * 64;
    const int lr   = lane & 15, lq = lane >> 4;

    int sAidx[4], sBidx[4];
#pragma unroll
    for (int i = 0; i < 4; ++i) {
        int mi = wm + 16 * i + lr;
        sAidx[i] = mi * 4 + (lq ^ ((mi >> 1) & 3));
        int ni = wn + 16 * i + lr;
        sBidx[i] = ni * 4 + (lq ^ ((ni >> 1) & 3));
    }

    f32x4 acc[4][4] = {};

    for (int kt = 0; kt < KTOT; kt += 32) {
        __builtin_amdgcn_global_load_lds(
            (__attribute__((address_space(1))) void*)(void*)ga0,
            (__attribute__((address_space(3))) void*)la0, 16, 0, 0);
        __builtin_amdgcn_global_load_lds(
            (__attribute__((address_space(1))) void*)(void*)ga1,
            (__attribute__((address_space(3))) void*)la1, 16, 0, 0);
        __builtin_amdgcn_global_load_lds(
            (__attribute__((address_space(1))) void*)(void*)gb0,
            (__attribute__((address_space(3))) void*)lb0, 16, 0, 0);
        __builtin_amdgcn_global_load_lds(
            (__attribute__((address_space(1))) void*)(void*)gb1,
            (__attribute__((address_space(3))) void*)lb1, 16, 0, 0);
        ga0 += 32; ga1 += 32; gb0 += 32; gb1 += 32;
        __syncthreads();

        bf16x8 af[4], bfr[4];
#pragma unroll
        for (int i = 0; i < 4; ++i) af[i]  = __builtin_bit_cast(bf16x8, sA[sAidx[i]]);
#pragma unroll
        for (int j = 0; j < 4; ++j) bfr[j] = __builtin_bit_cast(bf16x8, sB[sBidx[j]]);

#pragma unroll
        for (int i = 0; i < 4; ++i)
#pragma unroll
            for (int j = 0; j < 4; ++j)
                acc[i][j] = __builtin_amdgcn_mfma_f32_16x16x32_bf16(af[i], bfr[j],
                                                                    acc[i][j], 0, 0, 0);
        __syncthreads();
    }

    // epilogue: C/D layout col=lane&15, row=(lane>>4)*4+r.
    // Transposed store: lane's 4 regs are 4 consecutive m -> one ushort4 (8B).
#pragma unroll
    for (int j = 0; j < 4; ++j) {
        int gn = n0 + wn + 16 * j + lr;
        float bj = bias[gn];
#pragma unroll
        for (int i = 0; i < 4; ++i) {
            int rowb = m0 + wm + 16 * i + lq * 4;
            alignas(8) unsigned short pk[4];
#pragma unroll
            for (int r = 0; r < 4; ++r) pk[r] = f2bf(acc[i][j][r] + bj);
            *(int2*)(GT + (size_t)gn * MTOT + rowb) = *(const int2*)pk;
        }
    }
}

// ---------------------------------------------------------------------------
// K3: chunked fo-pool scan, block-local. Block = 256 threads = HT(32) h x SC(8)
// chunks; grid = B * (H/HT) = 256 blocks. Gates read from GT[n][m] so each
// thread's chain is contiguous -> bf16x8 loads.
__global__ __launch_bounds__(256) void scan_fo(const unsigned short* __restrict__ GT,
                                               float* __restrict__ out) {
    __shared__ float lP[SC][HT];
    __shared__ float lC[SC][HT];
    __shared__ float lI[SC][HT];

    const int tid   = threadIdx.x;
    const int h_loc = tid & (HT - 1);     // h fastest for store coalescing
    const int s     = tid >> 5;           // chunk index
    const int b     = blockIdx.x >> 4;
    const int h0    = (blockIdx.x & 15) * HT;
    const int h     = h0 + h_loc;

    const size_t mbase = (size_t)b * TLEN + (size_t)s * LC;
    const unsigned short* gz = GT + (size_t)h * MTOT + mbase;
    const unsigned short* gf = GT + (size_t)(DCH + h) * MTOT + mbase;
    const unsigned short* go = GT + (size_t)(2 * DCH + h) * MTOT + mbase;

    // ---- phase A: chunk aggregate (P = prod f, C = fo-pool with c0=0)
    float P = 1.f, c = 0.f;
    for (int k = 0; k < LC; k += 8) {
        bf16x8 zv = *(const bf16x8*)(gz + k);
        bf16x8 fv = *(const bf16x8*)(gf + k);
#pragma unroll
        for (int r = 0; r < 8; ++r) {
            float f = sigmoidf_((float)fv[r]);
            float z = 2.f * sigmoidf_(2.f * (float)zv[r]) - 1.f;   // tanh
            c = f * c + (1.f - f) * z;
            P *= f;
        }
    }
    lP[s][h_loc] = P;
    lC[s][h_loc] = c;
    __syncthreads();

    // ---- phase B: exclusive scan across the 8 chunks (one thread per h)
    if (tid < HT) {
        float cc = 0.f;
#pragma unroll
        for (int ss = 0; ss < SC; ++ss) {
            lI[ss][tid] = cc;
            cc = lP[ss][tid] * cc + lC[ss][tid];
        }
    }
    __syncthreads();

    // ---- phase C: recompute chunk with correct c_init, write outputs
    c = lI[s][h_loc];
    const size_t BTH = (size_t)NB * TLEN * DCH;
    float* oC  = out + mbase * DCH + h;
    float* oOC = oC + BTH;
    for (int k = 0; k < LC; k += 8) {
        bf16x8 zv = *(const bf16x8*)(gz + k);
        bf16x8 fv = *(const bf16x8*)(gf + k);
        bf16x8 ov = *(const bf16x8*)(go + k);
#pragma unroll
        for (int r = 0; r < 8; ++r) {
            float f = sigmoidf_((float)fv[r]);
            float z = 2.f * sigmoidf_(2.f * (float)zv[r]) - 1.f;
            float o = sigmoidf_((float)ov[r]);
            c = f * c + (1.f - f) * z;
            oC[(size_t)(k + r) * DCH]  = c;
            oOC[(size_t)(k + r) * DCH] = o * c;
        }
    }
}

// ---------------------------------------------------------------------------
extern "C" void kernel_launch(void* const* d_in, const int* in_sizes, int n_in,
                              void* d_out, int out_size, void* d_ws, size_t ws_size,
                              hipStream_t stream) {
    const float* in   = (const float*)d_in[0];   // [16,2048,512] f32
    const float* w    = (const float*)d_in[1];   // [1536,512,2] f32
    const float* bias = (const float*)d_in[2];   // [1536] f32
    float* out = (float*)d_out;                  // [2][16,2048,512] f32

    unsigned short* Abf = (unsigned short*)d_ws;
    unsigned short* Bbf = Abf + (size_t)MTOT * 1024;
    unsigned short* GT  = Bbf + (size_t)NTOT * 1024;

    make_A<<<dim3(16384), dim3(256), 0, stream>>>(in, Abf);
    make_B<<<dim3(3072),  dim3(256), 0, stream>>>(w, Bbf);
    gemm_gates<<<dim3(3072), dim3(256), 0, stream>>>(Abf, Bbf, bias, GT);
    scan_fo<<<dim3(NB * (DCH / HT)), dim3(256), 0, stream>>>(GT, out);
}